// Round 10
// baseline (260.910 us; speedup 1.0000x reference)
//
#include <hip/hip_runtime.h>

// ArcFace loss, MI355X. B=512, D=512, C=64000, s=64, m=0.5.
// R10: R9 pipeline with ZERO live-across-barrier temporaries. W(s+1) is
// loaded (nontemporal) AND packed to bufB[cur^1] entirely inside iter s's
// MFMA phase, so w0/w1/af/bfr are all phase-local: peak arch VGPR ~62
// + 64 acc AGPR = 126 <= 128 budget -> no scratch spills (R9's 86 MB
// WRITE_SIZE + reload latency chains). One barrier per iter. Pack uses
// the R9-verified 0-conflict XOR layout kcl*512 + (col^kcl)*8.

#define B_N 512
#define D_N 512
#define C_N 64000
#define S_SCALE 64.0f
#define MARGIN 0.5f
#define EPS_C 1e-7f
#define NREP 16

typedef unsigned short ushort_t;
typedef __attribute__((ext_vector_type(8))) short short8;   // 8 bf16 (4 VGPRs)
typedef __attribute__((ext_vector_type(4))) float floatx4;  // MFMA acc
typedef __attribute__((ext_vector_type(4))) float fvec4;

__device__ __forceinline__ ushort_t f2bf(float f) {
    unsigned int u = __float_as_uint(f);
    u += 0x7fffu + ((u >> 16) & 1u);  // round-to-nearest-even
    return (ushort_t)(u >> 16);
}

// Normalize x rows -> bf16 in fragment-linear layout:
//   xnT element addr = (kc*512 + row)*8 + j,  kc = k/8 in [0,64), j = k%8.
// Blocks 0..127: 4 rows each. Block 128: zero rowsum replicas.
__global__ void xprep_kernel(const float* __restrict__ x,
                             ushort_t* __restrict__ xnT,
                             float* __restrict__ rowsumR) {
    int b = blockIdx.x;
    int t = threadIdx.x;
    if (b == 128) {
#pragma unroll
        for (int i = 0; i < NREP * B_N / 256; ++i)
            rowsumR[i * 256 + t] = 0.0f;
        return;
    }
    int row  = b * 4 + (t >> 6);
    int lane = t & 63;
    const float4* p = (const float4*)(x + (size_t)row * D_N);
    float4 v0 = p[lane * 2];
    float4 v1 = p[lane * 2 + 1];
    float ss = v0.x*v0.x + v0.y*v0.y + v0.z*v0.z + v0.w*v0.w
             + v1.x*v1.x + v1.y*v1.y + v1.z*v1.z + v1.w*v1.w;
#pragma unroll
    for (int off = 32; off > 0; off >>= 1) ss += __shfl_xor(ss, off);
    float sc = 1.0f / fmaxf(sqrtf(ss), 1e-12f);
    uint4 o;
    o.x = (unsigned)f2bf(v0.x*sc) | ((unsigned)f2bf(v0.y*sc) << 16);
    o.y = (unsigned)f2bf(v0.z*sc) | ((unsigned)f2bf(v0.w*sc) << 16);
    o.z = (unsigned)f2bf(v1.x*sc) | ((unsigned)f2bf(v1.y*sc) << 16);
    o.w = (unsigned)f2bf(v1.z*sc) | ((unsigned)f2bf(v1.w*sc) << 16);
    *((uint4*)(xnT + ((size_t)(lane << 9) + row) * 8)) = o;
}

// One block = 64 classes x all 512 rows. 8 waves; wave w owns rows
// [w*64, w*64+64) x cols [0,64) as 4x4 mfma_f32_16x16x32_bf16 frags.
// Per iter s (BK=64): thread t (col=t>>3, kcl=t&7) owns W[col][s*64+
// kcl*8..+7]. Iter s's phase: issue nt-load W(s+1); af/bfr/MFMA for s;
// pack W(s+1) -> bufB[cur^1]; barrier. All temporaries phase-local.
__global__ __launch_bounds__(512, 4)
void gemm_fused_kernel(const float* __restrict__ W,
                       const ushort_t* __restrict__ xnT,
                       const int* __restrict__ y,
                       float* __restrict__ rowsumR,
                       float* __restrict__ tgt) {
    __shared__ ushort_t bufB[2][4096];   // 2 x 8 KB bf16 frag tiles
    __shared__ float    rnormS[64];      // 1/||W_col||
    __shared__ float    rowacc[512];     // per-row exp-sums

    int t    = threadIdx.x;
    int lane = t & 63;
    int w    = t >> 6;
    int lq   = lane >> 4;
    int lc   = lane & 15;
    int cn0  = blockIdx.x * 64;
    int col  = t >> 3;    // 0..63
    int kcl  = t & 7;     // 8-elem k-chunk within the 64-k step

    const fvec4* gW = (const fvec4*)(W + (size_t)(cn0 + col) * D_N + kcl * 8);
    ushort_t* myslot[2] = { &bufB[0][kcl * 512 + (col ^ kcl) * 8],
                            &bufB[1][kcl * 512 + (col ^ kcl) * 8] };

    const ushort_t* apT[4];
#pragma unroll
    for (int tm = 0; tm < 4; tm++)
        apT[tm] = xnT + ((size_t)lq * 512 + w * 64 + tm * 16 + lc) * 8;

    floatx4 acc[4][4];
#pragma unroll
    for (int i = 0; i < 4; i++)
#pragma unroll
        for (int j = 0; j < 4; j++) acc[i][j] = (floatx4){0.f, 0.f, 0.f, 0.f};
    float ssq = 0.0f;

    // ---- prologue: load + pack W(0) into bufB[0] ----
    {
        fvec4 w0 = __builtin_nontemporal_load(gW);
        fvec4 w1 = __builtin_nontemporal_load(gW + 1);
        ssq += w0.x*w0.x + w0.y*w0.y + w0.z*w0.z + w0.w*w0.w
             + w1.x*w1.x + w1.y*w1.y + w1.z*w1.z + w1.w*w1.w;
        uint4 pk;
        pk.x = (unsigned)f2bf(w0.x) | ((unsigned)f2bf(w0.y) << 16);
        pk.y = (unsigned)f2bf(w0.z) | ((unsigned)f2bf(w0.w) << 16);
        pk.z = (unsigned)f2bf(w1.x) | ((unsigned)f2bf(w1.y) << 16);
        pk.w = (unsigned)f2bf(w1.z) | ((unsigned)f2bf(w1.w) << 16);
        *(uint4*)myslot[0] = pk;
    }
    __syncthreads();

    for (int s = 0; s < 8; ++s) {
        int cur = s & 1;
        // issue next-iter W loads at phase top (latency covered by the
        // af loads + 32 MFMA below; consumed only at phase end)
        fvec4 w0, w1;
        if (s < 7) {
            w0 = __builtin_nontemporal_load(gW + (s + 1) * 16);
            w1 = __builtin_nontemporal_load(gW + (s + 1) * 16 + 1);
        }

        // ---- 2 x 32-k MFMA halves; af from L2 xnT, bfr from bufB ----
#pragma unroll
        for (int h = 0; h < 2; ++h) {
            short8 af[4], bfr[4];
#pragma unroll
            for (int tm = 0; tm < 4; tm++)
                af[tm] = *(const short8*)(apT[tm] + (s * 2 + h) * 16384);
            int kb = h * 4 + lq;
#pragma unroll
            for (int tn = 0; tn < 4; tn++)
                bfr[tn] = *(const short8*)
                    &bufB[cur][kb * 512 + ((tn * 16 + lc) ^ kb) * 8];
#pragma unroll
            for (int tm = 0; tm < 4; tm++)
#pragma unroll
                for (int tn = 0; tn < 4; tn++)
                    acc[tm][tn] = __builtin_amdgcn_mfma_f32_16x16x32_bf16(
                        af[tm], bfr[tn], acc[tm][tn], 0, 0, 0);
        }

        // ---- pack W(s+1) into the other buffer (phase-local temps) ----
        if (s < 7) {
            ssq += w0.x*w0.x + w0.y*w0.y + w0.z*w0.z + w0.w*w0.w
                 + w1.x*w1.x + w1.y*w1.y + w1.z*w1.z + w1.w*w1.w;
            uint4 pk;
            pk.x = (unsigned)f2bf(w0.x) | ((unsigned)f2bf(w0.y) << 16);
            pk.y = (unsigned)f2bf(w0.z) | ((unsigned)f2bf(w0.w) << 16);
            pk.z = (unsigned)f2bf(w1.x) | ((unsigned)f2bf(w1.y) << 16);
            pk.w = (unsigned)f2bf(w1.z) | ((unsigned)f2bf(w1.w) << 16);
            *(uint4*)myslot[cur ^ 1] = pk;
        }
        __syncthreads();
    }

    // ---- per-col rnorm from in-register sumsq (8 threads per col) ----
#pragma unroll
    for (int off = 1; off < 8; off <<= 1) ssq += __shfl_xor(ssq, off);
    if (kcl == 0) rnormS[col] = 1.0f / fmaxf(sqrtf(ssq), 1e-12f);
    __syncthreads();

    // ---- Epilogue. C/D layout: col = lane&15, row = lq*4 + reg. ----
    float rn[4];
#pragma unroll
    for (int tn = 0; tn < 4; tn++) rn[tn] = rnormS[tn * 16 + lc];
#pragma unroll
    for (int tm = 0; tm < 4; tm++) {
#pragma unroll
        for (int r = 0; r < 4; r++) {
            int lrow = w * 64 + tm * 16 + lq * 4 + r;  // 0..511, unique
            int yv   = y[lrow];
            float esum = 0.0f;
#pragma unroll
            for (int tn = 0; tn < 4; tn++) {
                int gcol = cn0 + tn * 16 + lc;
                float theta = acc[tm][tn][r] * rn[tn];
                if (gcol == yv) {
                    tgt[lrow] = theta;  // exactly one writer device-wide
                } else {
                    esum += __expf(S_SCALE * theta);
                }
            }
#pragma unroll
            for (int off = 1; off < 16; off <<= 1) esum += __shfl_xor(esum, off);
            if (lc == 0) rowacc[lrow] = esum;
        }
    }
    __syncthreads();
    atomicAdd(&rowsumR[(blockIdx.x & (NREP - 1)) * B_N + t], rowacc[t]);
}

__global__ void finalize_kernel(const float* __restrict__ rowsumR,
                                const float* __restrict__ tgt,
                                float* __restrict__ out) {
    __shared__ float red[256];
    int t = threadIdx.x;
    float s = 0.0f;
    for (int r = t; r < B_N; r += 256) {
        float rs = 0.0f;
#pragma unroll
        for (int i = 0; i < NREP; ++i) rs += rowsumR[i * B_N + r];
        float tv = tgt[r];
        tv = fminf(fmaxf(tv, -1.0f + EPS_C), 1.0f - EPS_C);
        float num = S_SCALE * cosf(acosf(tv) + MARGIN);
        float den = expf(num) + rs;
        s += num - logf(den);
    }
    red[t] = s;
    __syncthreads();
    for (int o = 128; o > 0; o >>= 1) {
        if (t < o) red[t] += red[t + o];
        __syncthreads();
    }
    if (t == 0) out[0] = -red[0] / (float)B_N;
}

extern "C" void kernel_launch(void* const* d_in, const int* in_sizes, int n_in,
                              void* d_out, int out_size, void* d_ws, size_t ws_size,
                              hipStream_t stream) {
    const float* x = (const float*)d_in[0];
    const int*   y = (const int*)d_in[1];
    const float* W = (const float*)d_in[2];
    float* out = (float*)d_out;

    char* ws = (char*)d_ws;
    ushort_t* xnT   = (ushort_t*)ws;                    // 512 KB (frag-linear)
    float* rowsumR  = (float*)(ws + 524288);            // 32 KB (16 replicas)
    float* tgt      = rowsumR + NREP * B_N;             // 2 KB

    xprep_kernel<<<129, 256, 0, stream>>>(x, xnT, rowsumR);
    gemm_fused_kernel<<<C_N / 64, 512, 0, stream>>>(W, xnT, y, rowsumR, tgt);
    finalize_kernel<<<1, 256, 0, stream>>>(rowsumR, tgt, out);
}